// Round 10
// baseline (170.636 us; speedup 1.0000x reference)
//
#include <hip/hip_runtime.h>
#include <hip/hip_bf16.h>

typedef __bf16 bf16;
typedef __bf16 bf16x4 __attribute__((ext_vector_type(4)));
typedef __bf16 bf16x8 __attribute__((ext_vector_type(8)));
typedef float f32x4 __attribute__((ext_vector_type(4)));
typedef unsigned int u32x4 __attribute__((ext_vector_type(4)));

#define SEQ   2048
#define NBAT  4
#define DM    1024
#define NH    16
#define HD    64
#define E3    3072

// ---------------- fp32 -> bf16 convert (x and W fused in one launch) ----------------
__global__ void cvt2_bf16_kernel(const float* __restrict__ a, bf16* __restrict__ oa, int na8,
                                 const float* __restrict__ b, bf16* __restrict__ ob, int nb8) {
  const int stride = gridDim.x * blockDim.x;
  const int ntot = na8 + nb8;
  for (int i = blockIdx.x * blockDim.x + threadIdx.x; i < ntot; i += stride) {
    const float* src;
    bf16* dst;
    int j;
    if (i < na8) { src = a; dst = oa; j = i; }
    else         { src = b; dst = ob; j = i - na8; }
    const float4* p = (const float4*)(src + (size_t)j * 8);
    float4 x = p[0];
    float4 y = p[1];
    bf16x8 o;
    o[0] = (bf16)x.x; o[1] = (bf16)x.y; o[2] = (bf16)x.z; o[3] = (bf16)x.w;
    o[4] = (bf16)y.x; o[5] = (bf16)y.y; o[6] = (bf16)y.z; o[7] = (bf16)y.w;
    *(bf16x8*)(dst + (size_t)j * 8) = o;
  }
}

// ---------------- QKV projection GEMM: Z = X * W^T + b ----------------
#define BM 128
#define BN 128
#define BK 32
#define KSTEPS (DM / BK)

__global__ __launch_bounds__(256, 2) void qkv_gemm_kernel(
    const bf16* __restrict__ A, const bf16* __restrict__ B,
    const float* __restrict__ bias, bf16* __restrict__ Z)
{
  __shared__ bf16 sA[2][BM * BK];
  __shared__ bf16 sB[2][BN * BK];

  const int tid  = threadIdx.x;
  const int lane = tid & 63;
  const int w    = tid >> 6;
  const int wr   = w >> 1;
  const int wc   = w & 1;
  const int m0   = blockIdx.x * BM;
  const int n0   = blockIdx.y * BN;

  const f32x4 z4 = {0.f, 0.f, 0.f, 0.f};
  f32x4 acc[4][4];
#pragma unroll
  for (int i = 0; i < 4; ++i)
#pragma unroll
    for (int j = 0; j < 4; ++j)
      acc[i][j] = z4;

  const int srow = w * 32 + (lane >> 2);
  const int skk  = (lane & 3) * 8;
  const bf16* gA = A + (size_t)m0 * DM;
  const bf16* gB = B + (size_t)n0 * DM;

  auto stage = [&](int buf, int t) {
    const int k0 = t * BK;
#pragma unroll
    for (int c = 0; c < 2; ++c)
      __builtin_amdgcn_global_load_lds(
          (const __attribute__((address_space(1))) unsigned int*)(gA + (size_t)(srow + c * 16) * DM + k0 + skk),
          (__attribute__((address_space(3))) unsigned int*)(&sA[buf][w * 1024 + c * 512]),
          16, 0, 0);
#pragma unroll
    for (int c = 0; c < 2; ++c)
      __builtin_amdgcn_global_load_lds(
          (const __attribute__((address_space(1))) unsigned int*)(gB + (size_t)(srow + c * 16) * DM + k0 + skk),
          (__attribute__((address_space(3))) unsigned int*)(&sB[buf][w * 1024 + c * 512]),
          16, 0, 0);
  };

  stage(0, 0);
  int cur = 0;
  const int arow = wr * 64 + (lane & 15);
  const int brow = wc * 64 + (lane & 15);
  const int kf   = (lane >> 4) * 8;

  for (int t = 0; t < KSTEPS; ++t) {
    __syncthreads();
    if (t + 1 < KSTEPS) stage(cur ^ 1, t + 1);
    bf16x8 af[4], bfr[4];
#pragma unroll
    for (int i = 0; i < 4; ++i)
      af[i] = *(const bf16x8*)&sA[cur][(arow + i * 16) * BK + kf];
#pragma unroll
    for (int j = 0; j < 4; ++j)
      bfr[j] = *(const bf16x8*)&sB[cur][(brow + j * 16) * BK + kf];
#pragma unroll
    for (int i = 0; i < 4; ++i)
#pragma unroll
      for (int j = 0; j < 4; ++j)
        acc[i][j] = __builtin_amdgcn_mfma_f32_16x16x32_bf16(af[i], bfr[j], acc[i][j], 0, 0, 0);
    cur ^= 1;
  }

#pragma unroll
  for (int i = 0; i < 4; ++i) {
#pragma unroll
    for (int j = 0; j < 4; ++j) {
      const int col = n0 + wc * 64 + j * 16 + (lane & 15);
      const float bb = bias[col];
#pragma unroll
      for (int r = 0; r < 4; ++r) {
        const int row = m0 + wr * 64 + i * 16 + (lane >> 4) * 4 + r;
        Z[(size_t)row * E3 + col] = (bf16)(acc[i][j][r] + bb);
      }
    }
  }
}

// ---------------- causal flash attention ----------------
// 8 waves x 16 q-rows (512 threads). Swapped QK^T: S^T = K·Q^T, q = lane&15.
// KB = QB = 128: every wave active every tile; diag mask only at t = T-1.
// PV k-permutation k(j) = c*32 + (j>>2)*16 + lhi*4 + (j&3); B-frag = lane's
// own softmax registers. sVT stores V[k][d] at [d][sigma(k) ^ X(d)],
// sigma = (k&96)|((k&12)<<1)|((k&16)>>2)|(k&3)  -> sigma(k(j)) = 32c+8*lhi+j
// (contiguous b128 PV read); X(d) = ((d^(d>>3))&7)<<3 spreads banks.
// sK staged via global_load_lds with XOR block swizzle blk=(d>>3)^(k&7)
// applied by pre-swizzling the per-lane global source (LDS dest linear).
// In-loop barrier = s_waitcnt vmcnt(2) lgkmcnt(0) + raw s_barrier: drains
// the stageK DMA (issued one full tile earlier) but lets the t+2 V-prefetch
// stay in flight across the barrier (counted-vmcnt, T3/T4).
#define QB 128
#define KB 128

__global__ __launch_bounds__(512, 4) void attn_kernel(
    const bf16* __restrict__ Z, float* __restrict__ out)
{
  __shared__ bf16 sK[2][KB][64];     // [buf][k][swizzled d]     32 KB
  __shared__ bf16 sVT[2][HD][KB];    // [buf][d][sigma(k)^X(d)]  32 KB

  const int tid   = threadIdx.x;
  const int lane  = tid & 63;
  const int w     = tid >> 6;        // 0..7
  const int l15   = lane & 15;
  const int lhi   = lane >> 4;
  const int l7    = l15 & 7;
  const int e2    = l15 >> 3;        // 0/1
  const int h     = blockIdx.y;
  const int n     = blockIdx.z;

  const size_t zb = (size_t)n * SEQ * E3;
  const int kcol0 = h * HD;
  const int qcol0 = DM + h * HD;
  const int vcol0 = 2 * DM + h * HD;

  const f32x4 z4 = {0.f, 0.f, 0.f, 0.f};
  const float scale = 0.03125f;   // D^-0.5 = 1/32 (full model dim)
  const float L2E   = 1.4426950408889634f;
  const float SL2E  = scale * L2E;
  const float DEFER = 4.0f;

  const u32x4 onesu = {0x3F803F80u, 0x3F803F80u, 0x3F803F80u, 0x3F803F80u};
  const bf16x8 onesf = __builtin_bit_cast(bf16x8, onesu);

  // V staging map: thread owns k-rows {c0row, c0row+64}, d-cols c0col..+7
  const int c0row = tid >> 3;          // 0..63
  const int t7    = tid & 7;
  const int c0col = t7 * 8;
  // sigma(c0row) (bit6 add for the +64 row is linear: sgk+64)
  const int sgk = (c0row & 96) | ((c0row & 12) << 1) | ((c0row & 16) >> 2) | (c0row & 3);

  // K staging map (global source pre-swizzle for global_load_lds)
  const int krow_off = 8 * w + (lane >> 3);            // k row within 1KB chunk
  const int kdblk    = ((lane & 7) ^ (lane >> 3)) * 8; // swizzled d offset

  const size_t ob = (size_t)n * SEQ * DM;

  bf16x8 vpre[2];
  auto vload = [&](int t) {
#pragma unroll
    for (int c = 0; c < 2; ++c)
      vpre[c] = *(const bf16x8*)&Z[zb + (size_t)(t * KB + c0row + 64 * c) * E3 + vcol0 + c0col];
  };
  auto lwriteV = [&](int buf) {
#pragma unroll
    for (int c = 0; c < 2; ++c)
#pragma unroll
      for (int j = 0; j < 8; ++j)
        sVT[buf][c0col + j][(sgk + 64 * c) ^ ((j ^ t7) << 3)] = vpre[c][j];
  };
  auto stageK = [&](int t, int buf) {
#pragma unroll
    for (int c = 0; c < 2; ++c)
      __builtin_amdgcn_global_load_lds(
          (const __attribute__((address_space(1))) unsigned int*)(
              Z + zb + (size_t)(t * KB + 64 * c + krow_off) * E3 + kcol0 + kdblk),
          (__attribute__((address_space(3))) unsigned int*)(&sK[buf][64 * c + 8 * w][0]),
          16, 0, 0);
  };

#pragma unroll 1
  for (int phase = 0; phase < 2; ++phase) {
    const int qtile = phase == 0 ? blockIdx.x : (15 - blockIdx.x);
    const int q0    = qtile * QB;
    const int qwave = q0 + w * 16;     // wave's 16 q-rows
    const int T     = qtile + 1;       // KV tiles this phase (KB == QB)

    // Q fragments (B-operand of swapped QK^T)
    bf16x8 qf[2];
    {
      const int qrow = qwave + l15;
#pragma unroll
      for (int kk = 0; kk < 2; ++kk)
        qf[kk] = *(const bf16x8*)&Z[zb + (size_t)qrow * E3 + qcol0 + kk * 32 + lhi * 8];
    }

    f32x4 accO[4];
    f32x4 accL;
#pragma unroll
    for (int dt = 0; dt < 4; ++dt) accO[dt] = z4;
    accL = z4;
    float mrow = -1e30f;

    // pipeline prologue
    stageK(0, 0);
    vload(0);
    lwriteV(0);
    vload(T > 1 ? 1 : 0);
    __syncthreads();

#pragma unroll 1
    for (int t = 0; t < T; ++t) {
      const int cur = t & 1;
      if (t + 1 < T) { stageK(t + 1, cur ^ 1); lwriteV(cur ^ 1); }
      asm volatile("" ::: "memory");          // keep stageK older than vload
      vload(t + 2 < T ? t + 2 : T - 1);       // clamp keeps vmcnt invariant

      union PB { unsigned int u[4]; bf16x8 v; };
      PB pb[4];

      // S^T = K·Q^T : C[k_local=lhi*4+r][q=l15] per kt (8 kt of 16 k)
      f32x4 st[8];
#pragma unroll
      for (int kt = 0; kt < 8; ++kt) st[kt] = z4;
      __builtin_amdgcn_s_setprio(1);
#pragma unroll
      for (int kt = 0; kt < 8; ++kt)
#pragma unroll
        for (int kk = 0; kk < 2; ++kk) {
          const int blk = ((4 * kk + lhi) ^ l7) * 8;
          bf16x8 kf = *(const bf16x8*)&sK[cur][kt * 16 + l15][blk];
          st[kt] = __builtin_amdgcn_mfma_f32_16x16x32_bf16(kf, qf[kk], st[kt], 0, 0, 0);
        }
      __builtin_amdgcn_s_setprio(0);

      const bool needmask = (t * KB + KB - 1) > qwave;
      float sv[32];
#pragma unroll
      for (int i = 0; i < 32; ++i) sv[i] = st[i >> 2][i & 3];
      if (needmask) {
        const int qg = qwave + l15;
#pragma unroll
        for (int i = 0; i < 32; ++i) {
          const int kg = t * KB + (i >> 2) * 16 + lhi * 4 + (i & 3);
          if (kg > qg) sv[i] = -1e32f;
        }
      }
      float mr = fmaxf(sv[0], sv[1]);
#pragma unroll
      for (int i = 2; i < 32; i += 2) mr = fmaxf(mr, fmaxf(sv[i], sv[i + 1]));
      mr = fmaxf(mr, __shfl_xor(mr, 16));
      mr = fmaxf(mr, __shfl_xor(mr, 32));
      const float mxs = mr * scale;

      // defer-max: rescale only when the row max outgrew m+THR
      if (__any(mxs > mrow + DEFER)) {
        const float mnew  = fmaxf(mrow, mxs);
        const float alpha = exp2f((mrow - mnew) * L2E);
        mrow = mnew;
#pragma unroll
        for (int dt = 0; dt < 4; ++dt) accO[dt] *= alpha;
        accL *= alpha;
      }

      // p = exp2(fma(s_raw, scale*log2e, -m*log2e)), packed in pairs
      const float mm = -mrow * L2E;
#pragma unroll
      for (int c = 0; c < 4; ++c)
#pragma unroll
        for (int i = 0; i < 4; ++i) {
          const float p0 = exp2f(fmaf(sv[c * 8 + 2 * i],     SL2E, mm));
          const float p1 = exp2f(fmaf(sv[c * 8 + 2 * i + 1], SL2E, mm));
          const bf16 b0 = (bf16)p0;
          const bf16 b1 = (bf16)p1;
          pb[c].u[i] = (unsigned int)__builtin_bit_cast(unsigned short, b0)
                     | ((unsigned int)__builtin_bit_cast(unsigned short, b1) << 16);
        }

      __builtin_amdgcn_s_setprio(1);
      // denominator via ones-MFMA
#pragma unroll
      for (int c = 0; c < 4; ++c)
        accL = __builtin_amdgcn_mfma_f32_16x16x32_bf16(onesf, pb[c].v, accL, 0, 0, 0);

      // O^T += V^T·P^T : av = single b128 (sigma-contiguous, XOR-swizzled)
#pragma unroll
      for (int c = 0; c < 4; ++c) {
#pragma unroll
        for (int dt = 0; dt < 4; ++dt) {
          const int idx = (32 * c + (lhi << 3)) ^ (((l7 ^ (2 * dt + e2)) & 7) << 3);
          const bf16x8 av = *(const bf16x8*)&sVT[cur][dt * 16 + l15][idx];
          accO[dt] = __builtin_amdgcn_mfma_f32_16x16x32_bf16(av, pb[c].v, accO[dt], 0, 0, 0);
        }
      }
      __builtin_amdgcn_s_setprio(0);

      if (t + 1 < T) {
        // counted-vmcnt barrier: drain stageK(t+1) (2 oldest), let the
        // 2 vload(t+2) loads fly across; drain own ds ops.
        asm volatile("s_waitcnt vmcnt(2) lgkmcnt(0)" ::: "memory");
        __builtin_amdgcn_s_barrier();
        asm volatile("" ::: "memory");
      } else {
        __syncthreads();   // phase-end: full drain
      }
    }

    // phase epilogue: normalize, float4 stores
    {
      const float inv  = 1.f / accL[0];
      const int   qrow = qwave + l15;
#pragma unroll
      for (int dt = 0; dt < 4; ++dt) {
        float4 o;
        o.x = accO[dt][0] * inv;
        o.y = accO[dt][1] * inv;
        o.z = accO[dt][2] * inv;
        o.w = accO[dt][3] * inv;
        *(float4*)&out[ob + (size_t)qrow * DM + h * HD + dt * 16 + lhi * 4] = o;
      }
    }
  }
}

extern "C" void kernel_launch(void* const* d_in, const int* in_sizes, int n_in,
                              void* d_out, int out_size, void* d_ws, size_t ws_size,
                              hipStream_t stream) {
  const float* x    = (const float*)d_in[0];
  const float* W    = (const float*)d_in[1];
  const float* bias = (const float*)d_in[2];
  float* out = (float*)d_out;

  bf16* xb = (bf16*)d_ws;
  bf16* Wb = xb + (size_t)NBAT * SEQ * DM;
  bf16* Zb = Wb + (size_t)E3 * DM;

  cvt2_bf16_kernel<<<1536, 256, 0, stream>>>(x, xb, NBAT * SEQ * DM / 8,
                                             W, Wb, E3 * DM / 8);

  dim3 g1(NBAT * SEQ / BM, E3 / BN);
  qkv_gemm_kernel<<<g1, 256, 0, stream>>>(xb, Wb, bias, Zb);

  dim3 g2(SEQ / (2 * QB), NH, NBAT);   // 8 pair-blocks: qtile b then 15-b
  attn_kernel<<<g2, 512, 0, stream>>>(Zb, out);
}

// Round 11
// 165.772 us; speedup vs baseline: 1.0293x; 1.0293x over previous
//
#include <hip/hip_runtime.h>
#include <hip/hip_bf16.h>

typedef __bf16 bf16;
typedef __bf16 bf16x4 __attribute__((ext_vector_type(4)));
typedef __bf16 bf16x8 __attribute__((ext_vector_type(8)));
typedef float f32x4 __attribute__((ext_vector_type(4)));
typedef unsigned int u32x4 __attribute__((ext_vector_type(4)));

#define SEQ   2048
#define NBAT  4
#define DM    1024
#define NH    16
#define HD    64
#define E3    3072

// ---------------- fp32 -> bf16 convert (x and W fused in one launch) ----------------
__global__ void cvt2_bf16_kernel(const float* __restrict__ a, bf16* __restrict__ oa, int na8,
                                 const float* __restrict__ b, bf16* __restrict__ ob, int nb8) {
  const int stride = gridDim.x * blockDim.x;
  const int ntot = na8 + nb8;
  for (int i = blockIdx.x * blockDim.x + threadIdx.x; i < ntot; i += stride) {
    const float* src;
    bf16* dst;
    int j;
    if (i < na8) { src = a; dst = oa; j = i; }
    else         { src = b; dst = ob; j = i - na8; }
    const float4* p = (const float4*)(src + (size_t)j * 8);
    float4 x = p[0];
    float4 y = p[1];
    bf16x8 o;
    o[0] = (bf16)x.x; o[1] = (bf16)x.y; o[2] = (bf16)x.z; o[3] = (bf16)x.w;
    o[4] = (bf16)y.x; o[5] = (bf16)y.y; o[6] = (bf16)y.z; o[7] = (bf16)y.w;
    *(bf16x8*)(dst + (size_t)j * 8) = o;
  }
}

// ---------------- QKV projection GEMM: Z = X * W^T + b ----------------
#define BM 128
#define BN 128
#define BK 32
#define KSTEPS (DM / BK)

__global__ __launch_bounds__(256, 2) void qkv_gemm_kernel(
    const bf16* __restrict__ A, const bf16* __restrict__ B,
    const float* __restrict__ bias, bf16* __restrict__ Z)
{
  __shared__ bf16 sA[2][BM * BK];
  __shared__ bf16 sB[2][BN * BK];

  const int tid  = threadIdx.x;
  const int lane = tid & 63;
  const int w    = tid >> 6;
  const int wr   = w >> 1;
  const int wc   = w & 1;
  const int m0   = blockIdx.x * BM;
  const int n0   = blockIdx.y * BN;

  const f32x4 z4 = {0.f, 0.f, 0.f, 0.f};
  f32x4 acc[4][4];
#pragma unroll
  for (int i = 0; i < 4; ++i)
#pragma unroll
    for (int j = 0; j < 4; ++j)
      acc[i][j] = z4;

  const int srow = w * 32 + (lane >> 2);
  const int skk  = (lane & 3) * 8;
  const bf16* gA = A + (size_t)m0 * DM;
  const bf16* gB = B + (size_t)n0 * DM;

  auto stage = [&](int buf, int t) {
    const int k0 = t * BK;
#pragma unroll
    for (int c = 0; c < 2; ++c)
      __builtin_amdgcn_global_load_lds(
          (const __attribute__((address_space(1))) unsigned int*)(gA + (size_t)(srow + c * 16) * DM + k0 + skk),
          (__attribute__((address_space(3))) unsigned int*)(&sA[buf][w * 1024 + c * 512]),
          16, 0, 0);
#pragma unroll
    for (int c = 0; c < 2; ++c)
      __builtin_amdgcn_global_load_lds(
          (const __attribute__((address_space(1))) unsigned int*)(gB + (size_t)(srow + c * 16) * DM + k0 + skk),
          (__attribute__((address_space(3))) unsigned int*)(&sB[buf][w * 1024 + c * 512]),
          16, 0, 0);
  };

  stage(0, 0);
  int cur = 0;
  const int arow = wr * 64 + (lane & 15);
  const int brow = wc * 64 + (lane & 15);
  const int kf   = (lane >> 4) * 8;

  for (int t = 0; t < KSTEPS; ++t) {
    __syncthreads();
    if (t + 1 < KSTEPS) stage(cur ^ 1, t + 1);
    bf16x8 af[4], bfr[4];
#pragma unroll
    for (int i = 0; i < 4; ++i)
      af[i] = *(const bf16x8*)&sA[cur][(arow + i * 16) * BK + kf];
#pragma unroll
    for (int j = 0; j < 4; ++j)
      bfr[j] = *(const bf16x8*)&sB[cur][(brow + j * 16) * BK + kf];
#pragma unroll
    for (int i = 0; i < 4; ++i)
#pragma unroll
      for (int j = 0; j < 4; ++j)
        acc[i][j] = __builtin_amdgcn_mfma_f32_16x16x32_bf16(af[i], bfr[j], acc[i][j], 0, 0, 0);
    cur ^= 1;
  }

#pragma unroll
  for (int i = 0; i < 4; ++i) {
#pragma unroll
    for (int j = 0; j < 4; ++j) {
      const int col = n0 + wc * 64 + j * 16 + (lane & 15);
      const float bb = bias[col];
#pragma unroll
      for (int r = 0; r < 4; ++r) {
        const int row = m0 + wr * 64 + i * 16 + (lane >> 4) * 4 + r;
        Z[(size_t)row * E3 + col] = (bf16)(acc[i][j][r] + bb);
      }
    }
  }
}

// ---------------- causal flash attention ----------------
// 8 waves x 16 q-rows (512 threads). Swapped QK^T: S^T = K·Q^T, q = lane&15.
// KB = QB = 128; diag mask only at t = T-1, and only fragment kt==w needs
// per-element compares (kt>w fully masked, kt<w untouched).
// In-place st[8] softmax (no sv copy) to stay under the VGPR cap (round-10
// lesson: st+sv copies spilled -> +13MB scratch WRITE traffic).
// sVT stores V[k][d] at [d][sigma(k)^X(d)], sigma makes PV reads contiguous
// b128; sK staged via global_load_lds with pre-swizzled global source.
// In-loop barrier = s_waitcnt vmcnt(2) lgkmcnt(0) + s_barrier (counted-vmcnt:
// the 2 V-prefetch loads stay in flight across the barrier).
#define QB 128
#define KB 128

__global__ __launch_bounds__(512, 4) void attn_kernel(
    const bf16* __restrict__ Z, float* __restrict__ out)
{
  __shared__ bf16 sK[2][KB][64];     // [buf][k][swizzled d]     32 KB
  __shared__ bf16 sVT[2][HD][KB];    // [buf][d][sigma(k)^X(d)]  32 KB

  const int tid   = threadIdx.x;
  const int lane  = tid & 63;
  const int w     = tid >> 6;        // 0..7
  const int l15   = lane & 15;
  const int lhi   = lane >> 4;
  const int l7    = l15 & 7;
  const int e2    = l15 >> 3;        // 0/1
  const int h     = blockIdx.y;
  const int n     = blockIdx.z;

  const size_t zb = (size_t)n * SEQ * E3;
  const int kcol0 = h * HD;
  const int qcol0 = DM + h * HD;
  const int vcol0 = 2 * DM + h * HD;

  const f32x4 z4 = {0.f, 0.f, 0.f, 0.f};
  const f32x4 neg4 = {-1e32f, -1e32f, -1e32f, -1e32f};
  const float scale = 0.03125f;   // D^-0.5 = 1/32 (full model dim)
  const float L2E   = 1.4426950408889634f;
  const float SL2E  = scale * L2E;
  const float DEFER = 4.0f;

  const u32x4 onesu = {0x3F803F80u, 0x3F803F80u, 0x3F803F80u, 0x3F803F80u};
  const bf16x8 onesf = __builtin_bit_cast(bf16x8, onesu);

  // V staging map: thread owns k-rows {c0row, c0row+64}, d-cols c0col..+7
  const int c0row = tid >> 3;          // 0..63
  const int t7    = tid & 7;
  const int c0col = t7 * 8;
  const int sgk = (c0row & 96) | ((c0row & 12) << 1) | ((c0row & 16) >> 2) | (c0row & 3);

  // K staging map (global source pre-swizzle for global_load_lds)
  const int krow_off = 8 * w + (lane >> 3);            // k row within 1KB chunk
  const int kdblk    = ((lane & 7) ^ (lane >> 3)) * 8; // swizzled d offset

  const size_t ob = (size_t)n * SEQ * DM;

  bf16x8 vpre[2];
  auto vload = [&](int t) {
#pragma unroll
    for (int c = 0; c < 2; ++c)
      vpre[c] = *(const bf16x8*)&Z[zb + (size_t)(t * KB + c0row + 64 * c) * E3 + vcol0 + c0col];
  };
  auto lwriteV = [&](int buf) {
#pragma unroll
    for (int c = 0; c < 2; ++c)
#pragma unroll
      for (int j = 0; j < 8; ++j)
        sVT[buf][c0col + j][(sgk + 64 * c) ^ ((j ^ t7) << 3)] = vpre[c][j];
  };
  auto stageK = [&](int t, int buf) {
#pragma unroll
    for (int c = 0; c < 2; ++c)
      __builtin_amdgcn_global_load_lds(
          (const __attribute__((address_space(1))) unsigned int*)(
              Z + zb + (size_t)(t * KB + 64 * c + krow_off) * E3 + kcol0 + kdblk),
          (__attribute__((address_space(3))) unsigned int*)(&sK[buf][64 * c + 8 * w][0]),
          16, 0, 0);
  };

#pragma unroll 1
  for (int phase = 0; phase < 2; ++phase) {
    const int qtile = phase == 0 ? blockIdx.x : (15 - blockIdx.x);
    const int q0    = qtile * QB;
    const int qwave = q0 + w * 16;     // wave's 16 q-rows
    const int T     = qtile + 1;       // KV tiles this phase (KB == QB)

    // Q fragments (B-operand of swapped QK^T)
    bf16x8 qf[2];
    {
      const int qrow = qwave + l15;
#pragma unroll
      for (int kk = 0; kk < 2; ++kk)
        qf[kk] = *(const bf16x8*)&Z[zb + (size_t)qrow * E3 + qcol0 + kk * 32 + lhi * 8];
    }

    f32x4 accO[4];
    f32x4 accL;
#pragma unroll
    for (int dt = 0; dt < 4; ++dt) accO[dt] = z4;
    accL = z4;
    float mrow = -1e30f;

    // pipeline prologue
    stageK(0, 0);
    vload(0);
    lwriteV(0);
    vload(T > 1 ? 1 : 0);
    __syncthreads();

#pragma unroll 1
    for (int t = 0; t < T; ++t) {
      const int cur = t & 1;
      if (t + 1 < T) { stageK(t + 1, cur ^ 1); lwriteV(cur ^ 1); }
      asm volatile("" ::: "memory");          // keep stageK older than vload
      vload(t + 2 < T ? t + 2 : T - 1);       // clamp keeps vmcnt invariant

      // S^T = K·Q^T : st[kt][r], k_local = kt*16 + lhi*4 + r, q = l15
      f32x4 st[8];
#pragma unroll
      for (int kt = 0; kt < 8; ++kt) st[kt] = z4;
      __builtin_amdgcn_s_setprio(1);
#pragma unroll
      for (int kt = 0; kt < 8; ++kt)
#pragma unroll
        for (int kk = 0; kk < 2; ++kk) {
          const int blk = ((4 * kk + lhi) ^ l7) * 8;
          bf16x8 kf = *(const bf16x8*)&sK[cur][kt * 16 + l15][blk];
          st[kt] = __builtin_amdgcn_mfma_f32_16x16x32_bf16(kf, qf[kk], st[kt], 0, 0, 0);
        }
      __builtin_amdgcn_s_setprio(0);

      // diagonal mask (in place): only at the last tile; kt>w fully masked,
      // kt==w per-element, kt<w untouched
      if (t == T - 1) {
        const int qg = l15;   // q within wave; k within fragment kt==w: lhi*4+r
#pragma unroll
        for (int kt = 0; kt < 8; ++kt) {
          if (kt > w) st[kt] = neg4;
          else if (kt == w) {
#pragma unroll
            for (int r = 0; r < 4; ++r)
              if (lhi * 4 + r > qg) st[kt][r] = -1e32f;
          }
        }
      }

      // row max (in place)
      float mr = fmaxf(st[0][0], st[0][1]);
#pragma unroll
      for (int kt = 0; kt < 8; ++kt)
#pragma unroll
        for (int r = (kt == 0 ? 2 : 0); r < 4; ++r) mr = fmaxf(mr, st[kt][r]);
      mr = fmaxf(mr, __shfl_xor(mr, 16));
      mr = fmaxf(mr, __shfl_xor(mr, 32));
      const float mxs = mr * scale;

      // defer-max: rescale only when the row max outgrew m+THR
      if (__any(mxs > mrow + DEFER)) {
        const float mnew  = fmaxf(mrow, mxs);
        const float alpha = exp2f((mrow - mnew) * L2E);
        mrow = mnew;
#pragma unroll
        for (int dt = 0; dt < 4; ++dt) accO[dt] *= alpha;
        accL *= alpha;
      }

      // p = exp2(fma(s_raw, scale*log2e, -m*log2e)); pack pairs, consume st
      const float mm = -mrow * L2E;
      bf16x8 pb[4];
#pragma unroll
      for (int c = 0; c < 4; ++c) {
        u32x4 pu;
#pragma unroll
        for (int i = 0; i < 4; ++i) {
          const int kt = 2 * c + (i >> 1);
          const int r  = (2 * i) & 3;
          const float p0 = exp2f(fmaf(st[kt][r],     SL2E, mm));
          const float p1 = exp2f(fmaf(st[kt][r + 1], SL2E, mm));
          const bf16 b0 = (bf16)p0;
          const bf16 b1 = (bf16)p1;
          pu[i] = (unsigned int)__builtin_bit_cast(unsigned short, b0)
                | ((unsigned int)__builtin_bit_cast(unsigned short, b1) << 16);
        }
        pb[c] = __builtin_bit_cast(bf16x8, pu);
      }

      __builtin_amdgcn_s_setprio(1);
      // denominator via ones-MFMA
#pragma unroll
      for (int c = 0; c < 4; ++c)
        accL = __builtin_amdgcn_mfma_f32_16x16x32_bf16(onesf, pb[c], accL, 0, 0, 0);

      // O^T += V^T·P^T : av = single b128 (sigma-contiguous, XOR-swizzled)
#pragma unroll
      for (int c = 0; c < 4; ++c) {
#pragma unroll
        for (int dt = 0; dt < 4; ++dt) {
          const int idx = (32 * c + (lhi << 3)) ^ (((l7 ^ (2 * dt + e2)) & 7) << 3);
          const bf16x8 av = *(const bf16x8*)&sVT[cur][dt * 16 + l15][idx];
          accO[dt] = __builtin_amdgcn_mfma_f32_16x16x32_bf16(av, pb[c], accO[dt], 0, 0, 0);
        }
      }
      __builtin_amdgcn_s_setprio(0);

      if (t + 1 < T) {
        // counted-vmcnt barrier: drain stageK(t+1) (2 oldest), let the
        // 2 vload loads fly across; drain own ds ops.
        asm volatile("s_waitcnt vmcnt(2) lgkmcnt(0)" ::: "memory");
        __builtin_amdgcn_s_barrier();
        asm volatile("" ::: "memory");
      } else {
        __syncthreads();   // phase-end: full drain
      }
    }

    // phase epilogue: normalize, float4 stores
    {
      const float inv  = 1.f / accL[0];
      const int   qrow = qwave + l15;
#pragma unroll
      for (int dt = 0; dt < 4; ++dt) {
        float4 o;
        o.x = accO[dt][0] * inv;
        o.y = accO[dt][1] * inv;
        o.z = accO[dt][2] * inv;
        o.w = accO[dt][3] * inv;
        *(float4*)&out[ob + (size_t)qrow * DM + h * HD + dt * 16 + lhi * 4] = o;
      }
    }
  }
}

extern "C" void kernel_launch(void* const* d_in, const int* in_sizes, int n_in,
                              void* d_out, int out_size, void* d_ws, size_t ws_size,
                              hipStream_t stream) {
  const float* x    = (const float*)d_in[0];
  const float* W    = (const float*)d_in[1];
  const float* bias = (const float*)d_in[2];
  float* out = (float*)d_out;

  bf16* xb = (bf16*)d_ws;
  bf16* Wb = xb + (size_t)NBAT * SEQ * DM;
  bf16* Zb = Wb + (size_t)E3 * DM;

  cvt2_bf16_kernel<<<1536, 256, 0, stream>>>(x, xb, NBAT * SEQ * DM / 8,
                                             W, Wb, E3 * DM / 8);

  dim3 g1(NBAT * SEQ / BM, E3 / BN);
  qkv_gemm_kernel<<<g1, 256, 0, stream>>>(xb, Wb, bias, Zb);

  dim3 g2(SEQ / (2 * QB), NH, NBAT);   // 8 pair-blocks: qtile b then 15-b
  attn_kernel<<<g2, 512, 0, stream>>>(Zb, out);
}